// Round 3
// baseline (290.498 us; speedup 1.0000x reference)
//
#include <hip/hip_runtime.h>
#include <stdint.h>

// Problem constants
#define BB 2
#define NN 2048
#define DD 512
#define HH 8
#define DHH 64
// bh count = 16, per-head Q/K/V = 2048*64 elems = 131072

typedef __attribute__((ext_vector_type(8))) short bf16x8;   // 8 bf16 = 4 VGPR
typedef __attribute__((ext_vector_type(4))) float f32x4;    // MFMA C/D frag

static __device__ __forceinline__ unsigned short f2bf(float f) {
    union { float f; unsigned u; } v; v.f = f;
    unsigned r = v.u + 0x7fffu + ((v.u >> 16) & 1u);  // RNE
    return (unsigned short)(r >> 16);
}

// pack two positive floats to bf16 pair (round-half-up; exp() outputs, no NaN/neg)
static __device__ __forceinline__ unsigned pkbf(float a, float b) {
    union { float f; unsigned u; } ua, ub; ua.f = a; ub.f = b;
    return ((ub.u + 0x8000u) & 0xffff0000u) | ((ua.u + 0x8000u) >> 16);
}

static __device__ __forceinline__ bf16x8 ld8(const unsigned short* p) {
    bf16x8 v; __builtin_memcpy(&v, p, 16); return v;
}

// ---------------- prep: cast x -> bf16, and cast+transpose 4 weights ----------------
// grid 2048+256 = 2304 blocks of 256
__global__ void ca_prep(const float* __restrict__ x,
                        const float* __restrict__ w0, const float* __restrict__ w1,
                        const float* __restrict__ w2, const float* __restrict__ w3,
                        unsigned short* __restrict__ xb, unsigned short* __restrict__ wts) {
    __shared__ float T[64][65];
    int bx = blockIdx.x;
    if (bx < 2048) {
        int gid = bx * 256 + threadIdx.x;
        float4 v = ((const float4*)x)[gid];
        ushort4 o;
        o.x = f2bf(v.x); o.y = f2bf(v.y); o.z = f2bf(v.z); o.w = f2bf(v.w);
        ((ushort4*)xb)[gid] = o;
        return;
    }
    int bb = bx - 2048;
    int z = bb >> 6, t = bb & 63;
    const float* W = (z == 0) ? w0 : (z == 1) ? w1 : (z == 2) ? w2 : w3;
    unsigned short* out = wts + z * 262144;
    int k0 = (t & 7) << 6, n0 = (t >> 3) << 6;
    int c = threadIdx.x & 63, r4 = threadIdx.x >> 6;
#pragma unroll
    for (int rr = 0; rr < 16; ++rr) {
        int r = r4 * 16 + rr;
        T[r][c] = W[(k0 + r) * 512 + n0 + c];
    }
    __syncthreads();
#pragma unroll
    for (int rr = 0; rr < 16; ++rr) {
        int r = r4 * 16 + rr;
        out[(n0 + r) * 512 + k0 + c] = f2bf(T[c][r]);
    }
}

// ------------- QKV projection GEMM (bf16 MFMA, fp32 acc), fused Q/K/V -------------
// grid (64 m-tiles, 24): by>>3 = z (0=Q,1=K,2=V), (by&7)*64 = n0.  Q pre-scaled by 0.125.
__global__ void ca_gemm_proj(const unsigned short* __restrict__ A,
                             const unsigned short* __restrict__ wts,
                             unsigned short* __restrict__ qkv) {
    int z = blockIdx.y >> 3;
    const unsigned short* BT = wts + z * 262144;
    unsigned short* out = qkv + z * 2097152;
    int w = threadIdx.x >> 6, lane = threadIdx.x & 63;
    int c = lane & 15, qd = lane >> 4;
    int m0 = blockIdx.x * 64 + w * 16;
    int n0 = (blockIdx.y & 7) * 64;
    f32x4 acc[4];
#pragma unroll
    for (int nb = 0; nb < 4; ++nb) acc[nb] = (f32x4){0.f, 0.f, 0.f, 0.f};
    const unsigned short* Ap = A + (m0 + c) * 512 + qd * 8;
    const unsigned short* Bp = BT + (n0 + c) * 512 + qd * 8;
    for (int k0 = 0; k0 < 512; k0 += 32) {
        bf16x8 a = ld8(Ap + k0);
#pragma unroll
        for (int nb = 0; nb < 4; ++nb) {
            bf16x8 b = ld8(Bp + nb * (16 * 512) + k0);
            acc[nb] = __builtin_amdgcn_mfma_f32_16x16x32_bf16(a, b, acc[nb], 0, 0, 0);
        }
    }
    float scale = (z == 0) ? 0.125f : 1.0f;   // fold attention scale into Q
#pragma unroll
    for (int nb = 0; nb < 4; ++nb) {
#pragma unroll
        for (int r = 0; r < 4; ++r) {
            int row = m0 + qd * 4 + r;
            int col = n0 + nb * 16 + c;
            int b = row >> 11, i = row & 2047, h = col >> 6, d = col & 63;
            out[(((b << 3) + h) * 2048 + i) * 64 + d] = f2bf(acc[nb][r] * scale);
        }
    }
}

// ------------- V transpose: [bh][N][DH] -> [bh][DH][N] -------------
__global__ void ca_transpose_v(const unsigned short* __restrict__ V,
                               unsigned short* __restrict__ VT) {
    __shared__ unsigned short T[64][65];
    int bh = blockIdx.x >> 5, it = blockIdx.x & 31;
    int i0 = it * 64;
    int c = threadIdx.x & 63, r4 = threadIdx.x >> 6;
    const unsigned short* src = V + bh * 131072;
    unsigned short* dst = VT + bh * 131072;
#pragma unroll
    for (int rr = 0; rr < 16; ++rr) {
        int i = r4 * 16 + rr;
        T[i][c] = src[(i0 + i) * 64 + c];
    }
    __syncthreads();
#pragma unroll
    for (int rr = 0; rr < 16; ++rr) {
        int d = r4 * 16 + rr;
        dst[d * 2048 + i0 + c] = T[c][d];
    }
}

// ------------- Flash attention v3 -------------
// grid 2048, block 256 = 4 waves. Block = 16 queries; wave w takes j-tiles {w,w+4,...},
// 4-way j-split; partial (o,l) summed across waves (exact: no max rescale needed,
// |logit*0.125| <= ~1.4 so plain sum-exp cannot overflow).
// XCD swizzle: bx&7 selects head group so each XCD's L2 serves only 2 heads' K/V.
// Q pre-scaled by 0.125 (proj epilogue); rel_pos scaled by 0.125 at LDS fill.
// LDS: P slab (4KB) unioned with reduction slab (15.4KB) — disjoint phases, barrier-guarded.
__global__ __launch_bounds__(256, 8)
void ca_flash(const unsigned short* __restrict__ Q,
              const unsigned short* __restrict__ K,
              const unsigned short* __restrict__ VT,
              const float* __restrict__ rel_pos,
              const float* __restrict__ c_emb,
              unsigned short* __restrict__ Ob) {
    __shared__ __align__(16) char smem[16392];
    unsigned (*Ptu)[16][16] = (unsigned (*)[16][16])smem;   // [wave][row][col] packed bf16 pairs
    float* red   = (float*)smem;                            // [3][64][20] floats, overlaps Ptu
    float* lrel  = (float*)(smem + 15360);                  // 129 floats (pre-scaled by 0.125)
    float* lgate = (float*)(smem + 15876);                  // 129 floats

    int bx = blockIdx.x;
    int xcd = bx & 7, slot = bx >> 3;           // slot 0..255
    int bh = xcd + ((slot >> 7) << 3);          // heads {xcd, xcd+8} per XCD
    int it = slot & 127;
    int b = bh >> 3, h = bh & 7;
    int w = threadIdx.x >> 6, lane = threadIdx.x & 63;
    int c = lane & 15, qd = lane >> 4;
    int i0 = it * 16;

    if (threadIdx.x < 129) {
        lrel[threadIdx.x]  = rel_pos[threadIdx.x * 8 + h] * 0.125f;
        lgate[threadIdx.x] = c_emb[threadIdx.x * 8 + h];
    }
    __syncthreads();

    const unsigned short* Qh = Q  + bh * 131072;
    const unsigned short* Kh = K  + bh * 131072;
    const unsigned short* Vh = VT + bh * 131072;

    bf16x8 aq0 = ld8(Qh + (i0 + c) * 64 + qd * 8);
    bf16x8 aq1 = ld8(Qh + (i0 + c) * 64 + 32 + qd * 8);

    f32x4 o[4];
    float lp[4] = {0.f, 0.f, 0.f, 0.f};
#pragma unroll
    for (int db = 0; db < 4; ++db) o[db] = (f32x4){0.f, 0.f, 0.f, 0.f};
    int iq = i0 + qd * 4;

    for (int t = 0; t < 16; ++t) {
        int j0 = (t * 4 + w) * 32;
        // K frags, interleaved columns: s0 col c <-> j0+2c, s1 col c <-> j0+2c+1
        bf16x8 bk0a = ld8(Kh + (j0 + 2 * c) * 64 + qd * 8);
        bf16x8 bk0b = ld8(Kh + (j0 + 2 * c) * 64 + 32 + qd * 8);
        bf16x8 bk1a = ld8(Kh + (j0 + 2 * c + 1) * 64 + qd * 8);
        bf16x8 bk1b = ld8(Kh + (j0 + 2 * c + 1) * 64 + 32 + qd * 8);
        bf16x8 bv[4];
#pragma unroll
        for (int db = 0; db < 4; ++db)
            bv[db] = ld8(Vh + (db * 16 + c) * 2048 + j0 + qd * 8);

        f32x4 s0 = (f32x4){0.f, 0.f, 0.f, 0.f};
        f32x4 s1 = (f32x4){0.f, 0.f, 0.f, 0.f};
        s0 = __builtin_amdgcn_mfma_f32_16x16x32_bf16(aq0, bk0a, s0, 0, 0, 0);
        s0 = __builtin_amdgcn_mfma_f32_16x16x32_bf16(aq1, bk0b, s0, 0, 0, 0);
        s1 = __builtin_amdgcn_mfma_f32_16x16x32_bf16(aq0, bk1a, s1, 0, 0, 0);
        s1 = __builtin_amdgcn_mfma_f32_16x16x32_bf16(aq1, bk1b, s1, 0, 0, 0);

        bool lowc  = (j0 + 31 - i0) <= -64;     // whole tile clamps to d=0
        bool highc = (j0 - (i0 + 15)) >= 64;    // whole tile clamps to d=128
        if (lowc || highc) {
            int d = lowc ? 0 : 128;
            float bb = lrel[d];                 // wave-uniform broadcast
            float g  = lgate[d];
#pragma unroll
            for (int r = 0; r < 4; ++r) {
                float t0 = __expf(s0[r] + bb);
                float t1 = __expf(s1[r] + bb);
                lp[r] += t0 + t1;
                Ptu[w][qd * 4 + r][c] = pkbf(t0 * g, t1 * g);
            }
        } else {
#pragma unroll
            for (int r = 0; r < 4; ++r) {
                int i = iq + r;
                int j = j0 + 2 * c;
                int d0 = j - i;     d0 = (d0 < -64) ? -64 : (d0 > 64 ? 64 : d0); d0 += 64;
                int d1 = j + 1 - i; d1 = (d1 < -64) ? -64 : (d1 > 64 ? 64 : d1); d1 += 64;
                float t0 = __expf(s0[r] + lrel[d0]);
                float t1 = __expf(s1[r] + lrel[d1]);
                lp[r] += t0 + t1;
                Ptu[w][qd * 4 + r][c] = pkbf(t0 * lgate[d0], t1 * lgate[d1]);
            }
        }
        // same-wave RAW on Ptu: lgkmcnt ordering, no barrier needed
        bf16x8 ap = ld8((const unsigned short*)&Ptu[w][c][0] + qd * 8);
#pragma unroll
        for (int db = 0; db < 4; ++db)
            o[db] = __builtin_amdgcn_mfma_f32_16x16x32_bf16(ap, bv[db], o[db], 0, 0, 0);
    }

    // ---- cross-wave combine (red overlaps Ptu: barrier before reuse) ----
    __syncthreads();
    if (w > 0) {
        float* dst = red + (w - 1) * (64 * 20) + lane * 20;
#pragma unroll
        for (int db = 0; db < 4; ++db)
#pragma unroll
            for (int r = 0; r < 4; ++r)
                dst[db * 4 + r] = o[db][r];
#pragma unroll
        for (int r = 0; r < 4; ++r)
            dst[16 + r] = lp[r];
    }
    __syncthreads();
    if (w == 0) {
#pragma unroll
        for (int ww = 0; ww < 3; ++ww) {
            const float* src = red + ww * (64 * 20) + lane * 20;
#pragma unroll
            for (int db = 0; db < 4; ++db)
#pragma unroll
                for (int r = 0; r < 4; ++r)
                    o[db][r] += src[db * 4 + r];
#pragma unroll
            for (int r = 0; r < 4; ++r)
                lp[r] += src[16 + r];
        }
#pragma unroll
        for (int r = 0; r < 4; ++r) {
            lp[r] += __shfl_xor(lp[r], 1);
            lp[r] += __shfl_xor(lp[r], 2);
            lp[r] += __shfl_xor(lp[r], 4);
            lp[r] += __shfl_xor(lp[r], 8);
        }
#pragma unroll
        for (int db = 0; db < 4; ++db)
#pragma unroll
            for (int r = 0; r < 4; ++r) {
                int row = b * 2048 + i0 + qd * 4 + r;
                int col = h * 64 + db * 16 + c;
                Ob[row * 512 + col] = f2bf(o[db][r] / lp[r]);
            }
    }
}

// ------------- Output GEMM: d_out = Ob @ Wo + bo (fp32 out) -------------
__global__ void ca_gemm_out(const unsigned short* __restrict__ A,
                            const unsigned short* __restrict__ BT,
                            const float* __restrict__ bias,
                            float* __restrict__ out) {
    int w = threadIdx.x >> 6, lane = threadIdx.x & 63;
    int c = lane & 15, qd = lane >> 4;
    int m0 = blockIdx.x * 64 + w * 16;
    int n0 = blockIdx.y * 64;
    f32x4 acc[4];
#pragma unroll
    for (int nb = 0; nb < 4; ++nb) acc[nb] = (f32x4){0.f, 0.f, 0.f, 0.f};
    const unsigned short* Ap = A + (m0 + c) * 512 + qd * 8;
    const unsigned short* Bp = BT + (n0 + c) * 512 + qd * 8;
    for (int k0 = 0; k0 < 512; k0 += 32) {
        bf16x8 a = ld8(Ap + k0);
#pragma unroll
        for (int nb = 0; nb < 4; ++nb) {
            bf16x8 bq = ld8(Bp + nb * (16 * 512) + k0);
            acc[nb] = __builtin_amdgcn_mfma_f32_16x16x32_bf16(a, bq, acc[nb], 0, 0, 0);
        }
    }
#pragma unroll
    for (int nb = 0; nb < 4; ++nb) {
#pragma unroll
        for (int r = 0; r < 4; ++r) {
            int row = m0 + qd * 4 + r;
            int col = n0 + nb * 16 + c;
            out[row * 512 + col] = acc[nb][r] + bias[col];
        }
    }
}

extern "C" void kernel_launch(void* const* d_in, const int* in_sizes, int n_in,
                              void* d_out, int out_size, void* d_ws, size_t ws_size,
                              hipStream_t stream) {
    const float* x   = (const float*)d_in[0];
    const float* Wq  = (const float*)d_in[1];
    const float* Wk  = (const float*)d_in[2];
    const float* Wv  = (const float*)d_in[3];
    const float* rel = (const float*)d_in[4];
    const float* cem = (const float*)d_in[5];
    const float* Wo  = (const float*)d_in[6];
    const float* bo  = (const float*)d_in[7];
    float* out = (float*)d_out;
    char* ws = (char*)d_ws;

    unsigned short* xb  = (unsigned short*)(ws);              // 4 MB
    unsigned short* wts = (unsigned short*)(ws + 4194304);    // 2 MB
    unsigned short* qkv = (unsigned short*)(ws + 6291456);    // 12 MB
    unsigned short* vt  = (unsigned short*)(ws + 18874368);   // 4 MB
    unsigned short* ob  = (unsigned short*)(ws + 23068672);   // 4 MB

    hipLaunchKernelGGL(ca_prep, dim3(2304), dim3(256), 0, stream, x, Wq, Wk, Wv, Wo, xb, wts);
    hipLaunchKernelGGL(ca_gemm_proj, dim3(64, 24), dim3(256), 0, stream, xb, wts, qkv);
    hipLaunchKernelGGL(ca_transpose_v, dim3(512), dim3(256), 0, stream, qkv + 2 * 2097152, vt);
    hipLaunchKernelGGL(ca_flash, dim3(2048), dim3(256), 0, stream,
                       qkv, qkv + 2097152, vt, rel, cem, ob);
    hipLaunchKernelGGL(ca_gemm_out, dim3(64, 8), dim3(256), 0, stream, ob, wts + 3 * 262144, bo, out);
}

// Round 4
// 213.746 us; speedup vs baseline: 1.3591x; 1.3591x over previous
//
#include <hip/hip_runtime.h>
#include <stdint.h>

// Problem constants
#define BB 2
#define NN 2048
#define DD 512
#define HH 8
#define DHH 64
// bh count = 16, per-head Q/K/V = 2048*64 elems = 131072

typedef __attribute__((ext_vector_type(8))) short bf16x8;   // 8 bf16 = 4 VGPR
typedef __attribute__((ext_vector_type(4))) float f32x4;    // MFMA C/D frag

static __device__ __forceinline__ unsigned short f2bf(float f) {
    union { float f; unsigned u; } v; v.f = f;
    unsigned r = v.u + 0x7fffu + ((v.u >> 16) & 1u);  // RNE
    return (unsigned short)(r >> 16);
}

// pack two positive floats to bf16 pair (round-half-up; exp() outputs, no NaN/neg)
static __device__ __forceinline__ unsigned pkbf(float a, float b) {
    union { float f; unsigned u; } ua, ub; ua.f = a; ub.f = b;
    return ((ub.u + 0x8000u) & 0xffff0000u) | ((ua.u + 0x8000u) >> 16);
}

static __device__ __forceinline__ bf16x8 ld8(const unsigned short* p) {
    bf16x8 v; __builtin_memcpy(&v, p, 16); return v;
}

// ---------------- prep: cast x -> bf16, and cast+transpose 4 weights ----------------
__global__ void ca_prep(const float* __restrict__ x,
                        const float* __restrict__ w0, const float* __restrict__ w1,
                        const float* __restrict__ w2, const float* __restrict__ w3,
                        unsigned short* __restrict__ xb, unsigned short* __restrict__ wts) {
    __shared__ float T[64][65];
    int bx = blockIdx.x;
    if (bx < 2048) {
        int gid = bx * 256 + threadIdx.x;
        float4 v = ((const float4*)x)[gid];
        ushort4 o;
        o.x = f2bf(v.x); o.y = f2bf(v.y); o.z = f2bf(v.z); o.w = f2bf(v.w);
        ((ushort4*)xb)[gid] = o;
        return;
    }
    int bb = bx - 2048;
    int z = bb >> 6, t = bb & 63;
    const float* W = (z == 0) ? w0 : (z == 1) ? w1 : (z == 2) ? w2 : w3;
    unsigned short* out = wts + z * 262144;
    int k0 = (t & 7) << 6, n0 = (t >> 3) << 6;
    int c = threadIdx.x & 63, r4 = threadIdx.x >> 6;
#pragma unroll
    for (int rr = 0; rr < 16; ++rr) {
        int r = r4 * 16 + rr;
        T[r][c] = W[(k0 + r) * 512 + n0 + c];
    }
    __syncthreads();
#pragma unroll
    for (int rr = 0; rr < 16; ++rr) {
        int r = r4 * 16 + rr;
        out[(n0 + r) * 512 + k0 + c] = f2bf(T[c][r]);
    }
}

// ------------- QKV projection GEMM: 2 m-tiles/wave sharing B frags -------------
// grid (32, 24): by>>3 = z (0=Q,1=K,2=V), (by&7)*64 = n0.  Q pre-scaled by 0.125.
__global__ __launch_bounds__(256, 4)
void ca_gemm_proj(const unsigned short* __restrict__ A,
                  const unsigned short* __restrict__ wts,
                  unsigned short* __restrict__ qkv) {
    int z = blockIdx.y >> 3;
    const unsigned short* BT = wts + z * 262144;
    unsigned short* out = qkv + z * 2097152;
    int w = threadIdx.x >> 6, lane = threadIdx.x & 63;
    int c = lane & 15, qd = lane >> 4;
    int m0 = blockIdx.x * 128 + w * 16;          // wave covers m0 and m0+64
    int n0 = (blockIdx.y & 7) * 64;
    f32x4 acc[2][4];
#pragma unroll
    for (int mt = 0; mt < 2; ++mt)
#pragma unroll
        for (int nb = 0; nb < 4; ++nb) acc[mt][nb] = (f32x4){0.f, 0.f, 0.f, 0.f};
    const unsigned short* Ap0 = A + (m0 + c) * 512 + qd * 8;
    const unsigned short* Ap1 = Ap0 + 64 * 512;
    const unsigned short* Bp  = BT + (n0 + c) * 512 + qd * 8;
#pragma unroll 4
    for (int k0 = 0; k0 < 512; k0 += 32) {
        bf16x8 a0 = ld8(Ap0 + k0);
        bf16x8 a1 = ld8(Ap1 + k0);
#pragma unroll
        for (int nb = 0; nb < 4; ++nb) {
            bf16x8 b = ld8(Bp + nb * (16 * 512) + k0);
            acc[0][nb] = __builtin_amdgcn_mfma_f32_16x16x32_bf16(a0, b, acc[0][nb], 0, 0, 0);
            acc[1][nb] = __builtin_amdgcn_mfma_f32_16x16x32_bf16(a1, b, acc[1][nb], 0, 0, 0);
        }
    }
    float scale = (z == 0) ? 0.125f : 1.0f;      // fold attention scale into Q
#pragma unroll
    for (int mt = 0; mt < 2; ++mt)
#pragma unroll
        for (int nb = 0; nb < 4; ++nb) {
#pragma unroll
            for (int r = 0; r < 4; ++r) {
                int row = m0 + mt * 64 + qd * 4 + r;
                int col = n0 + nb * 16 + c;
                int b = row >> 11, i = row & 2047, h = col >> 6, d = col & 63;
                out[(((b << 3) + h) * 2048 + i) * 64 + d] = f2bf(acc[mt][nb][r] * scale);
            }
        }
}

// ------------- V transpose: [bh][N][DH] -> [bh][DH][N] -------------
__global__ void ca_transpose_v(const unsigned short* __restrict__ V,
                               unsigned short* __restrict__ VT) {
    __shared__ unsigned short T[64][65];
    int bh = blockIdx.x >> 5, it = blockIdx.x & 31;
    int i0 = it * 64;
    int c = threadIdx.x & 63, r4 = threadIdx.x >> 6;
    const unsigned short* src = V + bh * 131072;
    unsigned short* dst = VT + bh * 131072;
#pragma unroll
    for (int rr = 0; rr < 16; ++rr) {
        int i = r4 * 16 + rr;
        T[i][c] = src[(i0 + i) * 64 + c];
    }
    __syncthreads();
#pragma unroll
    for (int rr = 0; rr < 16; ++rr) {
        int d = r4 * 16 + rr;
        dst[d * 2048 + i0 + c] = T[c][d];
    }
}

// ------------- Flash attention v4 -------------
// grid 1024, block 256 = 4 waves. Block = 32 queries (2 q-tiles of 16);
// wave w takes j-tiles {w, w+4, ...} (4-way j-split); partial (o,l) summed across
// waves at the end (exact: no max rescale; |scaled logit| <= ~1.4, no overflow).
// XCD swizzle: bx&7 -> each XCD's L2 serves only heads {xcd, xcd+8}.
// Q pre-scaled by 0.125 in proj; rel_pos scaled by 0.125 at LDS fill.
// K frags for t+1 prefetched into registers during iteration t (hides L2 latency).
// LDS: reduction slab overlaps per-wave P slabs (disjoint phases, barrier-guarded).
__global__ __launch_bounds__(256, 4)
void ca_flash(const unsigned short* __restrict__ Q,
              const unsigned short* __restrict__ K,
              const unsigned short* __restrict__ VT,
              const float* __restrict__ rel_pos,
              const float* __restrict__ c_emb,
              unsigned short* __restrict__ Ob) {
    __shared__ __align__(16) char smem[32528];
    unsigned (*Ptu)[16][16] = (unsigned (*)[16][16])smem;   // [wave][row][col] packed bf16 pairs
    float* red   = (float*)smem;                            // [3][64][41] floats, overlaps Ptu
    float* lrel  = (float*)(smem + 31488);                  // 129 floats (pre-scaled 0.125)
    float* lgate = (float*)(smem + 32008);                  // 129 floats

    int bx = blockIdx.x;
    int xcd = bx & 7, slot = bx >> 3;           // slot 0..127
    int bh = xcd + ((slot >> 6) << 3);          // heads {xcd, xcd+8} per XCD
    int it = slot & 63;
    int b = bh >> 3, h = bh & 7;
    int w = threadIdx.x >> 6, lane = threadIdx.x & 63;
    int c = lane & 15, qd = lane >> 4;
    int i0 = it * 32;

    if (threadIdx.x < 129) {
        lrel[threadIdx.x]  = rel_pos[threadIdx.x * 8 + h] * 0.125f;
        lgate[threadIdx.x] = c_emb[threadIdx.x * 8 + h];
    }
    __syncthreads();

    const unsigned short* Qh = Q  + bh * 131072;
    const unsigned short* Kh = K  + bh * 131072;
    const unsigned short* Vh = VT + bh * 131072;

    bf16x8 aq[2][2];
#pragma unroll
    for (int qt = 0; qt < 2; ++qt) {
        aq[qt][0] = ld8(Qh + (i0 + qt * 16 + c) * 64 + qd * 8);
        aq[qt][1] = ld8(Qh + (i0 + qt * 16 + c) * 64 + 32 + qd * 8);
    }

    f32x4 o2[2][4];
    float lp2[2][4];
#pragma unroll
    for (int qt = 0; qt < 2; ++qt)
#pragma unroll
        for (int db = 0; db < 4; ++db) {
            o2[qt][db] = (f32x4){0.f, 0.f, 0.f, 0.f};
            lp2[qt][db] = 0.f;
        }

    // prefetch K frags for t=0 (interleaved cols: s0 col c <-> j0+2c, s1 <-> j0+2c+1)
    int jp = w * 32;
    bf16x8 nk0a = ld8(Kh + (jp + 2 * c) * 64 + qd * 8);
    bf16x8 nk0b = ld8(Kh + (jp + 2 * c) * 64 + 32 + qd * 8);
    bf16x8 nk1a = ld8(Kh + (jp + 2 * c + 1) * 64 + qd * 8);
    bf16x8 nk1b = ld8(Kh + (jp + 2 * c + 1) * 64 + 32 + qd * 8);

#pragma unroll
    for (int t = 0; t < 16; ++t) {
        int j0 = (t * 4 + w) * 32;
        // V frags issued early: latency hidden by QK MFMAs + softmax VALU
        bf16x8 bv[4];
#pragma unroll
        for (int db = 0; db < 4; ++db)
            bv[db] = ld8(Vh + (db * 16 + c) * 2048 + j0 + qd * 8);
        bf16x8 bk0a = nk0a, bk0b = nk0b, bk1a = nk1a, bk1b = nk1b;
        if (t < 15) {
            int j1 = ((t + 1) * 4 + w) * 32;
            nk0a = ld8(Kh + (j1 + 2 * c) * 64 + qd * 8);
            nk0b = ld8(Kh + (j1 + 2 * c) * 64 + 32 + qd * 8);
            nk1a = ld8(Kh + (j1 + 2 * c + 1) * 64 + qd * 8);
            nk1b = ld8(Kh + (j1 + 2 * c + 1) * 64 + 32 + qd * 8);
        }

#pragma unroll
        for (int qt = 0; qt < 2; ++qt) {
            f32x4 s0 = (f32x4){0.f, 0.f, 0.f, 0.f};
            f32x4 s1 = (f32x4){0.f, 0.f, 0.f, 0.f};
            s0 = __builtin_amdgcn_mfma_f32_16x16x32_bf16(aq[qt][0], bk0a, s0, 0, 0, 0);
            s0 = __builtin_amdgcn_mfma_f32_16x16x32_bf16(aq[qt][1], bk0b, s0, 0, 0, 0);
            s1 = __builtin_amdgcn_mfma_f32_16x16x32_bf16(aq[qt][0], bk1a, s1, 0, 0, 0);
            s1 = __builtin_amdgcn_mfma_f32_16x16x32_bf16(aq[qt][1], bk1b, s1, 0, 0, 0);

            int iqt0 = i0 + qt * 16;
            int iq = iqt0 + qd * 4;
            bool lowc  = (j0 + 31 - iqt0) <= -64;   // whole tile clamps to d=0
            bool highc = (j0 - (iqt0 + 15)) >= 64;  // whole tile clamps to d=128
            if (lowc || highc) {
                int d = lowc ? 0 : 128;
                float bb = lrel[d];                 // wave-uniform broadcast
                float g  = lgate[d];
#pragma unroll
                for (int r = 0; r < 4; ++r) {
                    float t0 = __expf(s0[r] + bb);
                    float t1 = __expf(s1[r] + bb);
                    lp2[qt][r] += t0 + t1;
                    Ptu[w][qd * 4 + r][c] = pkbf(t0 * g, t1 * g);
                }
            } else {
#pragma unroll
                for (int r = 0; r < 4; ++r) {
                    int i = iq + r;
                    int j = j0 + 2 * c;
                    int d0 = j - i;     d0 = (d0 < -64) ? -64 : (d0 > 64 ? 64 : d0); d0 += 64;
                    int d1 = j + 1 - i; d1 = (d1 < -64) ? -64 : (d1 > 64 ? 64 : d1); d1 += 64;
                    float t0 = __expf(s0[r] + lrel[d0]);
                    float t1 = __expf(s1[r] + lrel[d1]);
                    lp2[qt][r] += t0 + t1;
                    Ptu[w][qd * 4 + r][c] = pkbf(t0 * lgate[d0], t1 * lgate[d1]);
                }
            }
            // same-wave RAW on Ptu: lgkmcnt ordering, no barrier needed
            bf16x8 ap = ld8((const unsigned short*)&Ptu[w][c][0] + qd * 8);
#pragma unroll
            for (int db = 0; db < 4; ++db)
                o2[qt][db] = __builtin_amdgcn_mfma_f32_16x16x32_bf16(ap, bv[db], o2[qt][db], 0, 0, 0);
        }
    }

    // ---- cross-wave combine (red overlaps Ptu: barrier before reuse) ----
    __syncthreads();
    if (w > 0) {
        float* dst = red + (w - 1) * (64 * 41) + lane * 41;
#pragma unroll
        for (int qt = 0; qt < 2; ++qt)
#pragma unroll
            for (int db = 0; db < 4; ++db)
#pragma unroll
                for (int r = 0; r < 4; ++r)
                    dst[qt * 16 + db * 4 + r] = o2[qt][db][r];
#pragma unroll
        for (int qt = 0; qt < 2; ++qt)
#pragma unroll
            for (int r = 0; r < 4; ++r)
                dst[32 + qt * 4 + r] = lp2[qt][r];
    }
    __syncthreads();
    if (w == 0) {
#pragma unroll
        for (int ww = 0; ww < 3; ++ww) {
            const float* src = red + ww * (64 * 41) + lane * 41;
#pragma unroll
            for (int qt = 0; qt < 2; ++qt) {
#pragma unroll
                for (int db = 0; db < 4; ++db)
#pragma unroll
                    for (int r = 0; r < 4; ++r)
                        o2[qt][db][r] += src[qt * 16 + db * 4 + r];
#pragma unroll
                for (int r = 0; r < 4; ++r)
                    lp2[qt][r] += src[32 + qt * 4 + r];
            }
        }
#pragma unroll
        for (int qt = 0; qt < 2; ++qt)
#pragma unroll
            for (int r = 0; r < 4; ++r) {
                lp2[qt][r] += __shfl_xor(lp2[qt][r], 1);
                lp2[qt][r] += __shfl_xor(lp2[qt][r], 2);
                lp2[qt][r] += __shfl_xor(lp2[qt][r], 4);
                lp2[qt][r] += __shfl_xor(lp2[qt][r], 8);
            }
#pragma unroll
        for (int qt = 0; qt < 2; ++qt)
#pragma unroll
            for (int db = 0; db < 4; ++db)
#pragma unroll
                for (int r = 0; r < 4; ++r) {
                    int row = b * 2048 + i0 + qt * 16 + qd * 4 + r;
                    int col = h * 64 + db * 16 + c;
                    Ob[row * 512 + col] = f2bf(o2[qt][db][r] / lp2[qt][r]);
                }
    }
}

// ------------- Output GEMM: 2 m-tiles/wave, d_out = Ob @ Wo + bo (fp32) -------------
// grid (32, 8)
__global__ __launch_bounds__(256, 4)
void ca_gemm_out(const unsigned short* __restrict__ A,
                 const unsigned short* __restrict__ BT,
                 const float* __restrict__ bias,
                 float* __restrict__ out) {
    int w = threadIdx.x >> 6, lane = threadIdx.x & 63;
    int c = lane & 15, qd = lane >> 4;
    int m0 = blockIdx.x * 128 + w * 16;
    int n0 = blockIdx.y * 64;
    f32x4 acc[2][4];
#pragma unroll
    for (int mt = 0; mt < 2; ++mt)
#pragma unroll
        for (int nb = 0; nb < 4; ++nb) acc[mt][nb] = (f32x4){0.f, 0.f, 0.f, 0.f};
    const unsigned short* Ap0 = A + (m0 + c) * 512 + qd * 8;
    const unsigned short* Ap1 = Ap0 + 64 * 512;
    const unsigned short* Bp  = BT + (n0 + c) * 512 + qd * 8;
#pragma unroll 4
    for (int k0 = 0; k0 < 512; k0 += 32) {
        bf16x8 a0 = ld8(Ap0 + k0);
        bf16x8 a1 = ld8(Ap1 + k0);
#pragma unroll
        for (int nb = 0; nb < 4; ++nb) {
            bf16x8 bq = ld8(Bp + nb * (16 * 512) + k0);
            acc[0][nb] = __builtin_amdgcn_mfma_f32_16x16x32_bf16(a0, bq, acc[0][nb], 0, 0, 0);
            acc[1][nb] = __builtin_amdgcn_mfma_f32_16x16x32_bf16(a1, bq, acc[1][nb], 0, 0, 0);
        }
    }
#pragma unroll
    for (int mt = 0; mt < 2; ++mt)
#pragma unroll
        for (int nb = 0; nb < 4; ++nb) {
#pragma unroll
            for (int r = 0; r < 4; ++r) {
                int row = m0 + mt * 64 + qd * 4 + r;
                int col = n0 + nb * 16 + c;
                out[row * 512 + col] = acc[mt][nb][r] + bias[col];
            }
        }
}

extern "C" void kernel_launch(void* const* d_in, const int* in_sizes, int n_in,
                              void* d_out, int out_size, void* d_ws, size_t ws_size,
                              hipStream_t stream) {
    const float* x   = (const float*)d_in[0];
    const float* Wq  = (const float*)d_in[1];
    const float* Wk  = (const float*)d_in[2];
    const float* Wv  = (const float*)d_in[3];
    const float* rel = (const float*)d_in[4];
    const float* cem = (const float*)d_in[5];
    const float* Wo  = (const float*)d_in[6];
    const float* bo  = (const float*)d_in[7];
    float* out = (float*)d_out;
    char* ws = (char*)d_ws;

    unsigned short* xb  = (unsigned short*)(ws);              // 4 MB
    unsigned short* wts = (unsigned short*)(ws + 4194304);    // 2 MB
    unsigned short* qkv = (unsigned short*)(ws + 6291456);    // 12 MB
    unsigned short* vt  = (unsigned short*)(ws + 18874368);   // 4 MB
    unsigned short* ob  = (unsigned short*)(ws + 23068672);   // 4 MB

    hipLaunchKernelGGL(ca_prep, dim3(2304), dim3(256), 0, stream, x, Wq, Wk, Wv, Wo, xb, wts);
    hipLaunchKernelGGL(ca_gemm_proj, dim3(32, 24), dim3(256), 0, stream, xb, wts, qkv);
    hipLaunchKernelGGL(ca_transpose_v, dim3(512), dim3(256), 0, stream, qkv + 2 * 2097152, vt);
    hipLaunchKernelGGL(ca_flash, dim3(1024), dim3(256), 0, stream,
                       qkv, qkv + 2097152, vt, rel, cem, ob);
    hipLaunchKernelGGL(ca_gemm_out, dim3(32, 8), dim3(256), 0, stream, ob, wts + 3 * 262144, bo, out);
}

// Round 5
// 192.498 us; speedup vs baseline: 1.5091x; 1.1104x over previous
//
#include <hip/hip_runtime.h>
#include <stdint.h>

// Problem constants
#define BB 2
#define NN 2048
#define DD 512
#define HH 8
#define DHH 64
// bh count = 16, per-head Q/K/V = 2048*64 elems = 131072

typedef __attribute__((ext_vector_type(8))) short bf16x8;   // 8 bf16 = 4 VGPR
typedef __attribute__((ext_vector_type(4))) float f32x4;    // MFMA C/D frag

static __device__ __forceinline__ unsigned short f2bf(float f) {
    union { float f; unsigned u; } v; v.f = f;
    unsigned r = v.u + 0x7fffu + ((v.u >> 16) & 1u);  // RNE
    return (unsigned short)(r >> 16);
}

// pack two positive floats to bf16 pair (round-half-up; exp() outputs, no NaN/neg)
static __device__ __forceinline__ unsigned pkbf(float a, float b) {
    union { float f; unsigned u; } ua, ub; ua.f = a; ub.f = b;
    return ((ub.u + 0x8000u) & 0xffff0000u) | ((ua.u + 0x8000u) >> 16);
}

static __device__ __forceinline__ bf16x8 ld8(const unsigned short* p) {
    bf16x8 v; __builtin_memcpy(&v, p, 16); return v;
}

// ---------------- prep: cast x -> bf16, and cast+transpose 4 weights ----------------
__global__ void ca_prep(const float* __restrict__ x,
                        const float* __restrict__ w0, const float* __restrict__ w1,
                        const float* __restrict__ w2, const float* __restrict__ w3,
                        unsigned short* __restrict__ xb, unsigned short* __restrict__ wts) {
    __shared__ float T[64][65];
    int bx = blockIdx.x;
    if (bx < 2048) {
        int gid = bx * 256 + threadIdx.x;
        float4 v = ((const float4*)x)[gid];
        ushort4 o;
        o.x = f2bf(v.x); o.y = f2bf(v.y); o.z = f2bf(v.z); o.w = f2bf(v.w);
        ((ushort4*)xb)[gid] = o;
        return;
    }
    int bb = bx - 2048;
    int z = bb >> 6, t = bb & 63;
    const float* W = (z == 0) ? w0 : (z == 1) ? w1 : (z == 2) ? w2 : w3;
    unsigned short* out = wts + z * 262144;
    int k0 = (t & 7) << 6, n0 = (t >> 3) << 6;
    int c = threadIdx.x & 63, r4 = threadIdx.x >> 6;
#pragma unroll
    for (int rr = 0; rr < 16; ++rr) {
        int r = r4 * 16 + rr;
        T[r][c] = W[(k0 + r) * 512 + n0 + c];
    }
    __syncthreads();
#pragma unroll
    for (int rr = 0; rr < 16; ++rr) {
        int r = r4 * 16 + rr;
        out[(n0 + r) * 512 + k0 + c] = f2bf(T[c][r]);
    }
}

// ------------- QKV projection GEMM: 2 m-tiles/wave sharing B frags -------------
// grid (32, 24): by>>3 = z (0=Q,1=K,2=V), (by&7)*64 = n0.  Q pre-scaled by 0.125.
// V (z==2) is written directly TRANSPOSED to vt[bh][d][i] (fuses old transpose kernel):
// the 4 accumulator rows r are consecutive i at fixed d -> one 8B ushort4 store.
__global__ __launch_bounds__(256, 4)
void ca_gemm_proj(const unsigned short* __restrict__ A,
                  const unsigned short* __restrict__ wts,
                  unsigned short* __restrict__ qkv,
                  unsigned short* __restrict__ vt) {
    int z = blockIdx.y >> 3;
    const unsigned short* BT = wts + z * 262144;
    unsigned short* out = qkv + z * 2097152;
    int w = threadIdx.x >> 6, lane = threadIdx.x & 63;
    int c = lane & 15, qd = lane >> 4;
    int m0 = blockIdx.x * 128 + w * 16;          // wave covers m0 and m0+64
    int n0 = (blockIdx.y & 7) * 64;
    f32x4 acc[2][4];
#pragma unroll
    for (int mt = 0; mt < 2; ++mt)
#pragma unroll
        for (int nb = 0; nb < 4; ++nb) acc[mt][nb] = (f32x4){0.f, 0.f, 0.f, 0.f};
    const unsigned short* Ap0 = A + (m0 + c) * 512 + qd * 8;
    const unsigned short* Ap1 = Ap0 + 64 * 512;
    const unsigned short* Bp  = BT + (n0 + c) * 512 + qd * 8;
#pragma unroll 4
    for (int k0 = 0; k0 < 512; k0 += 32) {
        bf16x8 a0 = ld8(Ap0 + k0);
        bf16x8 a1 = ld8(Ap1 + k0);
#pragma unroll
        for (int nb = 0; nb < 4; ++nb) {
            bf16x8 b = ld8(Bp + nb * (16 * 512) + k0);
            acc[0][nb] = __builtin_amdgcn_mfma_f32_16x16x32_bf16(a0, b, acc[0][nb], 0, 0, 0);
            acc[1][nb] = __builtin_amdgcn_mfma_f32_16x16x32_bf16(a1, b, acc[1][nb], 0, 0, 0);
        }
    }
    if (z == 2) {
        // V: write transposed [bh][d][i], 4 consecutive i packed per store
#pragma unroll
        for (int mt = 0; mt < 2; ++mt) {
            int ib = m0 + mt * 64 + qd * 4;      // i base (4-aligned)
            int b = ib >> 11, i = ib & 2047;
#pragma unroll
            for (int nb = 0; nb < 4; ++nb) {
                int col = n0 + nb * 16 + c;      // h*64 + d
                int h = col >> 6, d = col & 63;
                ushort4 pk;
                pk.x = f2bf(acc[mt][nb][0]); pk.y = f2bf(acc[mt][nb][1]);
                pk.z = f2bf(acc[mt][nb][2]); pk.w = f2bf(acc[mt][nb][3]);
                *(ushort4*)(vt + (((b << 3) + h) * 64 + d) * 2048 + i) = pk;
            }
        }
    } else {
        float scale = (z == 0) ? 0.125f : 1.0f;  // fold attention scale into Q
#pragma unroll
        for (int mt = 0; mt < 2; ++mt)
#pragma unroll
            for (int nb = 0; nb < 4; ++nb) {
#pragma unroll
                for (int r = 0; r < 4; ++r) {
                    int row = m0 + mt * 64 + qd * 4 + r;
                    int col = n0 + nb * 16 + c;
                    int b = row >> 11, i = row & 2047, h = col >> 6, d = col & 63;
                    out[(((b << 3) + h) * 2048 + i) * 64 + d] = f2bf(acc[mt][nb][r] * scale);
                }
            }
    }
}

// ------------- Flash attention v5 (R2 inner loop: no prefetch -> no spill) -------------
// grid 1024, block 256 = 4 waves. Block = 32 queries (2 q-tiles of 16);
// wave w takes j-tiles {w, w+4, ...} (4-way j-split); partial (o,l) summed across
// waves at the end (exact: no max rescale; |scaled logit| <= ~1.4, no overflow).
// XCD swizzle: bx&7 -> each XCD's L2 serves only heads {xcd, xcd+8}.
// Q pre-scaled by 0.125 in proj; rel_pos scaled by 0.125 at LDS fill.
// LDS: reduction slab overlaps per-wave P slabs (disjoint phases, barrier-guarded).
__global__ __launch_bounds__(256, 4)
void ca_flash(const unsigned short* __restrict__ Q,
              const unsigned short* __restrict__ K,
              const unsigned short* __restrict__ VT,
              const float* __restrict__ rel_pos,
              const float* __restrict__ c_emb,
              unsigned short* __restrict__ Ob) {
    __shared__ __align__(16) char smem[32528];
    unsigned (*Ptu)[16][16] = (unsigned (*)[16][16])smem;   // [wave][row][col] packed bf16 pairs
    float* red   = (float*)smem;                            // [3][64][41] floats, overlaps Ptu
    float* lrel  = (float*)(smem + 31488);                  // 129 floats (pre-scaled 0.125)
    float* lgate = (float*)(smem + 32008);                  // 129 floats

    int bx = blockIdx.x;
    int xcd = bx & 7, slot = bx >> 3;           // slot 0..127
    int bh = xcd + ((slot >> 6) << 3);          // heads {xcd, xcd+8} per XCD
    int it = slot & 63;
    int b = bh >> 3, h = bh & 7;
    int w = threadIdx.x >> 6, lane = threadIdx.x & 63;
    int c = lane & 15, qd = lane >> 4;
    int i0 = it * 32;

    if (threadIdx.x < 129) {
        lrel[threadIdx.x]  = rel_pos[threadIdx.x * 8 + h] * 0.125f;
        lgate[threadIdx.x] = c_emb[threadIdx.x * 8 + h];
    }
    __syncthreads();

    const unsigned short* Qh = Q  + bh * 131072;
    const unsigned short* Kh = K  + bh * 131072;
    const unsigned short* Vh = VT + bh * 131072;

    bf16x8 aq[2][2];
#pragma unroll
    for (int qt = 0; qt < 2; ++qt) {
        aq[qt][0] = ld8(Qh + (i0 + qt * 16 + c) * 64 + qd * 8);
        aq[qt][1] = ld8(Qh + (i0 + qt * 16 + c) * 64 + 32 + qd * 8);
    }

    f32x4 o2[2][4];
    float lp2[2][4];
#pragma unroll
    for (int qt = 0; qt < 2; ++qt)
#pragma unroll
        for (int db = 0; db < 4; ++db) {
            o2[qt][db] = (f32x4){0.f, 0.f, 0.f, 0.f};
            lp2[qt][db] = 0.f;
        }

    for (int t = 0; t < 16; ++t) {
        int j0 = (t * 4 + w) * 32;
        // K frags, interleaved columns: s0 col c <-> j0+2c, s1 col c <-> j0+2c+1
        bf16x8 bk0a = ld8(Kh + (j0 + 2 * c) * 64 + qd * 8);
        bf16x8 bk0b = ld8(Kh + (j0 + 2 * c) * 64 + 32 + qd * 8);
        bf16x8 bk1a = ld8(Kh + (j0 + 2 * c + 1) * 64 + qd * 8);
        bf16x8 bk1b = ld8(Kh + (j0 + 2 * c + 1) * 64 + 32 + qd * 8);
        bf16x8 bv[4];
#pragma unroll
        for (int db = 0; db < 4; ++db)
            bv[db] = ld8(Vh + (db * 16 + c) * 2048 + j0 + qd * 8);

#pragma unroll
        for (int qt = 0; qt < 2; ++qt) {
            f32x4 s0 = (f32x4){0.f, 0.f, 0.f, 0.f};
            f32x4 s1 = (f32x4){0.f, 0.f, 0.f, 0.f};
            s0 = __builtin_amdgcn_mfma_f32_16x16x32_bf16(aq[qt][0], bk0a, s0, 0, 0, 0);
            s0 = __builtin_amdgcn_mfma_f32_16x16x32_bf16(aq[qt][1], bk0b, s0, 0, 0, 0);
            s1 = __builtin_amdgcn_mfma_f32_16x16x32_bf16(aq[qt][0], bk1a, s1, 0, 0, 0);
            s1 = __builtin_amdgcn_mfma_f32_16x16x32_bf16(aq[qt][1], bk1b, s1, 0, 0, 0);

            int iqt0 = i0 + qt * 16;
            int iq = iqt0 + qd * 4;
            bool lowc  = (j0 + 31 - iqt0) <= -64;   // whole tile clamps to d=0
            bool highc = (j0 - (iqt0 + 15)) >= 64;  // whole tile clamps to d=128
            if (lowc || highc) {
                int d = lowc ? 0 : 128;
                float bb = lrel[d];                 // wave-uniform broadcast
                float g  = lgate[d];
#pragma unroll
                for (int r = 0; r < 4; ++r) {
                    float t0 = __expf(s0[r] + bb);
                    float t1 = __expf(s1[r] + bb);
                    lp2[qt][r] += t0 + t1;
                    Ptu[w][qd * 4 + r][c] = pkbf(t0 * g, t1 * g);
                }
            } else {
#pragma unroll
                for (int r = 0; r < 4; ++r) {
                    int i = iq + r;
                    int j = j0 + 2 * c;
                    int d0 = j - i;     d0 = (d0 < -64) ? -64 : (d0 > 64 ? 64 : d0); d0 += 64;
                    int d1 = j + 1 - i; d1 = (d1 < -64) ? -64 : (d1 > 64 ? 64 : d1); d1 += 64;
                    float t0 = __expf(s0[r] + lrel[d0]);
                    float t1 = __expf(s1[r] + lrel[d1]);
                    lp2[qt][r] += t0 + t1;
                    Ptu[w][qd * 4 + r][c] = pkbf(t0 * lgate[d0], t1 * lgate[d1]);
                }
            }
            // same-wave RAW on Ptu: lgkmcnt ordering, no barrier needed
            bf16x8 ap = ld8((const unsigned short*)&Ptu[w][c][0] + qd * 8);
#pragma unroll
            for (int db = 0; db < 4; ++db)
                o2[qt][db] = __builtin_amdgcn_mfma_f32_16x16x32_bf16(ap, bv[db], o2[qt][db], 0, 0, 0);
        }
    }

    // ---- cross-wave combine (red overlaps Ptu: barrier before reuse) ----
    __syncthreads();
    if (w > 0) {
        float* dst = red + (w - 1) * (64 * 41) + lane * 41;
#pragma unroll
        for (int qt = 0; qt < 2; ++qt)
#pragma unroll
            for (int db = 0; db < 4; ++db)
#pragma unroll
                for (int r = 0; r < 4; ++r)
                    dst[qt * 16 + db * 4 + r] = o2[qt][db][r];
#pragma unroll
        for (int qt = 0; qt < 2; ++qt)
#pragma unroll
            for (int r = 0; r < 4; ++r)
                dst[32 + qt * 4 + r] = lp2[qt][r];
    }
    __syncthreads();
    if (w == 0) {
#pragma unroll
        for (int ww = 0; ww < 3; ++ww) {
            const float* src = red + ww * (64 * 41) + lane * 41;
#pragma unroll
            for (int qt = 0; qt < 2; ++qt) {
#pragma unroll
                for (int db = 0; db < 4; ++db)
#pragma unroll
                    for (int r = 0; r < 4; ++r)
                        o2[qt][db][r] += src[qt * 16 + db * 4 + r];
#pragma unroll
                for (int r = 0; r < 4; ++r)
                    lp2[qt][r] += src[32 + qt * 4 + r];
            }
        }
#pragma unroll
        for (int qt = 0; qt < 2; ++qt)
#pragma unroll
            for (int r = 0; r < 4; ++r) {
                lp2[qt][r] += __shfl_xor(lp2[qt][r], 1);
                lp2[qt][r] += __shfl_xor(lp2[qt][r], 2);
                lp2[qt][r] += __shfl_xor(lp2[qt][r], 4);
                lp2[qt][r] += __shfl_xor(lp2[qt][r], 8);
            }
#pragma unroll
        for (int qt = 0; qt < 2; ++qt)
#pragma unroll
            for (int db = 0; db < 4; ++db)
#pragma unroll
                for (int r = 0; r < 4; ++r) {
                    int row = b * 2048 + i0 + qt * 16 + qd * 4 + r;
                    int col = h * 64 + db * 16 + c;
                    Ob[row * 512 + col] = f2bf(o2[qt][db][r] / lp2[qt][r]);
                }
    }
}

// ------------- Output GEMM: 2 m-tiles/wave, d_out = Ob @ Wo + bo (fp32) -------------
// grid (32, 8)
__global__ __launch_bounds__(256, 4)
void ca_gemm_out(const unsigned short* __restrict__ A,
                 const unsigned short* __restrict__ BT,
                 const float* __restrict__ bias,
                 float* __restrict__ out) {
    int w = threadIdx.x >> 6, lane = threadIdx.x & 63;
    int c = lane & 15, qd = lane >> 4;
    int m0 = blockIdx.x * 128 + w * 16;
    int n0 = blockIdx.y * 64;
    f32x4 acc[2][4];
#pragma unroll
    for (int mt = 0; mt < 2; ++mt)
#pragma unroll
        for (int nb = 0; nb < 4; ++nb) acc[mt][nb] = (f32x4){0.f, 0.f, 0.f, 0.f};
    const unsigned short* Ap0 = A + (m0 + c) * 512 + qd * 8;
    const unsigned short* Ap1 = Ap0 + 64 * 512;
    const unsigned short* Bp  = BT + (n0 + c) * 512 + qd * 8;
#pragma unroll 4
    for (int k0 = 0; k0 < 512; k0 += 32) {
        bf16x8 a0 = ld8(Ap0 + k0);
        bf16x8 a1 = ld8(Ap1 + k0);
#pragma unroll
        for (int nb = 0; nb < 4; ++nb) {
            bf16x8 bq = ld8(Bp + nb * (16 * 512) + k0);
            acc[0][nb] = __builtin_amdgcn_mfma_f32_16x16x32_bf16(a0, bq, acc[0][nb], 0, 0, 0);
            acc[1][nb] = __builtin_amdgcn_mfma_f32_16x16x32_bf16(a1, bq, acc[1][nb], 0, 0, 0);
        }
    }
#pragma unroll
    for (int mt = 0; mt < 2; ++mt)
#pragma unroll
        for (int nb = 0; nb < 4; ++nb) {
#pragma unroll
            for (int r = 0; r < 4; ++r) {
                int row = m0 + mt * 64 + qd * 4 + r;
                int col = n0 + nb * 16 + c;
                out[row * 512 + col] = acc[mt][nb][r] + bias[col];
            }
        }
}

extern "C" void kernel_launch(void* const* d_in, const int* in_sizes, int n_in,
                              void* d_out, int out_size, void* d_ws, size_t ws_size,
                              hipStream_t stream) {
    const float* x   = (const float*)d_in[0];
    const float* Wq  = (const float*)d_in[1];
    const float* Wk  = (const float*)d_in[2];
    const float* Wv  = (const float*)d_in[3];
    const float* rel = (const float*)d_in[4];
    const float* cem = (const float*)d_in[5];
    const float* Wo  = (const float*)d_in[6];
    const float* bo  = (const float*)d_in[7];
    float* out = (float*)d_out;
    char* ws = (char*)d_ws;

    unsigned short* xb  = (unsigned short*)(ws);              // 4 MB
    unsigned short* wts = (unsigned short*)(ws + 4194304);    // 2 MB
    unsigned short* qkv = (unsigned short*)(ws + 6291456);    // 12 MB (q,k; v slot unused)
    unsigned short* vt  = (unsigned short*)(ws + 18874368);   // 4 MB  vT bf16 [bh][DH][N]
    unsigned short* ob  = (unsigned short*)(ws + 23068672);   // 4 MB

    hipLaunchKernelGGL(ca_prep, dim3(2304), dim3(256), 0, stream, x, Wq, Wk, Wv, Wo, xb, wts);
    hipLaunchKernelGGL(ca_gemm_proj, dim3(32, 24), dim3(256), 0, stream, xb, wts, qkv, vt);
    hipLaunchKernelGGL(ca_flash, dim3(1024), dim3(256), 0, stream,
                       qkv, qkv + 2097152, vt, rel, cem, ob);
    hipLaunchKernelGGL(ca_gemm_out, dim3(32, 8), dim3(256), 0, stream, ob, wts + 3 * 262144, bo, out);
}